// Round 15
// baseline (448.165 us; speedup 1.0000x reference)
//
#include <hip/hip_runtime.h>
#include <math.h>

#define T_ 128

// ws offsets (floats)
#define OFF_M2      0         // [256][256]
#define OFF_WCOMBT  65536     // [128][1280]
#define OFF_BIAS    229376    // [1280]
#define OFF_WCT     230656    // [256][128]
#define OFF_XG2     263424    // [128 t][32 b][256 dim][4 gate]  (gate-packed)
#define OFF_BX2     4457728   // [128 t][32 b][256 d]
#define OFF_HSEQ    5506304   // [128 t][32 b][256 d]  (ht from LSTM chain)
#define OFF_HCSEQ   6554880   // [128 t][32 b][256 d]  (hn_partial from cfc chain)

#define SENTB 0xFFFFFFFFu

typedef float f4 __attribute__((ext_vector_type(4)));

__device__ __forceinline__ float sigm_f(float x) { return 1.0f / (1.0f + __expf(-x)); }
__device__ __forceinline__ float tanh_f(float x) { return 1.0f - 2.0f / (__expf(2.0f * x) + 1.0f); }

__device__ __forceinline__ unsigned long long aload_u64(const unsigned long long* p) {
  return __hip_atomic_load(p, __ATOMIC_RELAXED, __HIP_MEMORY_SCOPE_AGENT);
}
__device__ __forceinline__ void astore_f(float* p, float v) {
  __hip_atomic_store(p, v, __ATOMIC_RELAXED, __HIP_MEMORY_SCOPE_AGENT);
}
__device__ __forceinline__ bool bad_u64(unsigned long long v) {
  return (unsigned)v == SENTB || (unsigned)(v >> 32) == SENTB;
}

// ---------------- prep: WcombT, bias, WCT, M2, sentinel fill ----------------
__global__ __launch_bounds__(256) void prep_kernel(
    const float* __restrict__ W_ih, const float* __restrict__ W_B,
    const float* __restrict__ b_ih, const float* __restrict__ b_hh,
    const float* __restrict__ b_B,  const float* __restrict__ W_C,
    const float* __restrict__ W_A,  const float* __restrict__ tau,
    float* __restrict__ ws) {
  __shared__ float adrow[256];
  const int blk = blockIdx.x, tid = threadIdx.x;
  if (blk < 640) {            // WcombT[k][c], 163840 elems
    const int idx = blk * 256 + tid;
    const int k = idx / 1280, c = idx - k * 1280;
    ws[OFF_WCOMBT + idx] = (c < 1024) ? W_ih[c * 128 + k] : W_B[(c - 1024) * 128 + k];
  } else if (blk == 640) {    // bias[1280]
#pragma unroll
    for (int i = 0; i < 5; ++i) {
      const int id = i * 256 + tid;
      ws[OFF_BIAS + id] = (id < 1024) ? (b_ih[id] + b_hh[id]) : b_B[id - 1024];
    }
  } else if (blk < 769) {     // WCT[k][o], 32768
    const int idx = (blk - 641) * 256 + tid;
    const int k = idx >> 7, o = idx & 127;
    ws[OFF_WCT + idx] = W_C[o * 256 + k];
  } else if (blk < 1025) {    // M2 row i = (W_A D)(W_A D), D = diag(1/tau)
    const int i = blk - 769, k = tid;
    const float itk = 1.0f / tau[k];
    adrow[k] = W_A[i * 256 + k] * itk;
    __syncthreads();
    float s = 0.f;
#pragma unroll 8
    for (int m = 0; m < 256; ++m)
      s = fmaf(adrow[m], W_A[m * 256 + k], s);
    ws[OFF_M2 + i * 256 + k] = s * itk;
  } else {                    // sentinel fill (0xFFFFFFFF dwords), 8 MB
    uint4* dst = (uint4*)(ws + OFF_HSEQ);
    const uint4 sv = make_uint4(SENTB, SENTB, SENTB, SENTB);
    const int tg = (blk - 1025) * 256 + tid;  // 32768 threads x 16 uint4
#pragma unroll
    for (int i = 0; i < 16; ++i) dst[tg + i * 32768] = sv;
  }
}

// ---------------- xg/Bx precompute v2: 32 rows/block, 4-row reuse of WT ------
// xg2 written GATE-PACKED: xg2[((t*32+b)*256 + dim)*4 + gate]
__global__ __launch_bounds__(256) void xgt_kernel(
    const float* __restrict__ x, const float* __restrict__ WT,
    const float* __restrict__ bias, float* __restrict__ xg2,
    float* __restrict__ bx2) {
  __shared__ float xs[32 * 128];   // 16 KB
  const int tid = threadIdx.x;
  const int rt = blockIdx.x, ct = blockIdx.y;
  {
    const float4* src4 = (const float4*)(x + (size_t)rt * 4096);
    float4* d4 = (float4*)xs;
#pragma unroll
    for (int v = 0; v < 4; ++v) d4[v * 256 + tid] = src4[v * 256 + tid];
  }
  __syncthreads();
  const int rg = tid >> 5, cg = tid & 31;
  const int c0 = ct * 256 + cg * 8;
  const float4* b4 = (const float4*)(bias + c0);
  const float4 bA = b4[0], bB = b4[1];
  float a[4][8];
#pragma unroll
  for (int i = 0; i < 4; ++i) {
    a[i][0] = bA.x; a[i][1] = bA.y; a[i][2] = bA.z; a[i][3] = bA.w;
    a[i][4] = bB.x; a[i][5] = bB.y; a[i][6] = bB.z; a[i][7] = bB.w;
  }
  const float4* xr0 = (const float4*)(xs + (rg * 4 + 0) * 128);
  const float4* xr1 = (const float4*)(xs + (rg * 4 + 1) * 128);
  const float4* xr2 = (const float4*)(xs + (rg * 4 + 2) * 128);
  const float4* xr3 = (const float4*)(xs + (rg * 4 + 3) * 128);
#pragma unroll 2
  for (int k4 = 0; k4 < 32; ++k4) {
    const float4 xv0 = xr0[k4], xv1 = xr1[k4], xv2 = xr2[k4], xv3 = xr3[k4];
    const float xk[4][4] = {
        {xv0.x, xv0.y, xv0.z, xv0.w}, {xv1.x, xv1.y, xv1.z, xv1.w},
        {xv2.x, xv2.y, xv2.z, xv2.w}, {xv3.x, xv3.y, xv3.z, xv3.w}};
#pragma unroll
    for (int kk = 0; kk < 4; ++kk) {
      const float4* wp = (const float4*)(WT + (k4 * 4 + kk) * 1280 + c0);
      const float4 wA = wp[0], wB = wp[1];
      const float wv[8] = {wA.x, wA.y, wA.z, wA.w, wB.x, wB.y, wB.z, wB.w};
#pragma unroll
      for (int i = 0; i < 4; ++i)
#pragma unroll
        for (int j = 0; j < 8; ++j)
          a[i][j] = fmaf(wv[j], xk[i][kk], a[i][j]);
    }
  }
#pragma unroll
  for (int i = 0; i < 4; ++i) {
    const int row = rt * 32 + rg * 4 + i;   // = b*128 + t
    const int b = row >> 7, t = row & 127;
    if (ct < 4) {
      // gate-packed scatter: dim = cg*8+j, gate = ct
      float* dst = xg2 + (((size_t)(t * 32 + b) * 256 + cg * 8) * 4 + ct);
#pragma unroll
      for (int j = 0; j < 8; ++j) dst[j * 4] = a[i][j];
    } else {
      float4* d4 = (float4*)(bx2 + (size_t)(t * 32 + b) * 256 + cg * 8);
      d4[0] = make_float4(a[i][0], a[i][1], a[i][2], a[i][3]);
      d4[1] = make_float4(a[i][4], a[i][5], a[i][6], a[i][7]);
    }
  }
}

__device__ __forceinline__ float wc_elem(
    const float* __restrict__ W_A, const float* __restrict__ M2,
    const float* __restrict__ tau, int ci, float it_i, int kp) {
  if (kp < 256)      return W_A[ci * 256 + kp] / tau[kp];
  else if (kp < 512) return W_A[ci * 256 + (kp - 256)] * it_i;
  else               return 0.5f * M2[ci * 256 + (kp - 512)];
}

// ---------------- recurrence + fused output: 1024 blocks ----------------
// blocks [0,512): LSTM,  b = bix>>4, cb16 = bix&15, owns dims [16cb16, +16)
// blocks [512,1024): cfc, same mapping for rows.
// Tail: 4 y-rows per block, WCT staged through LDS in 16 chunks (shared by
// all 4 waves -> no redundant L2 streaming).
__global__ __launch_bounds__(256, 4) void recur_bp_kernel(
    const float* __restrict__ ts_all, const float* __restrict__ tau,
    const float* __restrict__ sigma, const float* __restrict__ W_hh,
    const float* __restrict__ W_A, const float* __restrict__ M2,
    const float* __restrict__ xg2, const float* __restrict__ bx2,
    float* __restrict__ hseq, float* __restrict__ hcseq,
    const float* __restrict__ WCT, const float* __restrict__ bC,
    float* __restrict__ y) {
  const int tid = threadIdx.x;
  const int lane = tid & 63, w = tid >> 6;
  const unsigned long long* hsq  = (const unsigned long long*)hseq;
  const unsigned long long* hcsq = (const unsigned long long*)hcseq;

  __shared__ float h_s[2][256];   // staged state (h or true hc), double-buffered
  __shared__ float q_s[2][768];   // cfc q vector
  __shared__ float ys_s[1024];    // tail: 4 hc rows
  __shared__ float wct_s[2048];   // tail: WCT chunk (16 k-rows x 128 cols)

  if (blockIdx.x < 512) {
    // ===================== LSTM (batch b, dims 16*cb16..) =====================
    const int b = blockIdx.x >> 4, cb16 = blockIdx.x & 15;
    const int kq = lane & 3;
    const int gt = (lane >> 2) & 3;
    const int dim = cb16 * 16 + 4 * w + (lane >> 4);
    const int grow = gt * 256 + dim;
    // INTERLEAVED k: this lane handles float4 indices i4*4 + kq.
    const f4* wsrc = (const f4*)(W_hh + grow * 256);
    f4 wq0  = wsrc[0 * 4 + kq],  wq1  = wsrc[1 * 4 + kq];
    f4 wq2  = wsrc[2 * 4 + kq],  wq3  = wsrc[3 * 4 + kq];
    f4 wq4  = wsrc[4 * 4 + kq],  wq5  = wsrc[5 * 4 + kq];
    f4 wq6  = wsrc[6 * 4 + kq],  wq7  = wsrc[7 * 4 + kq];
    f4 wq8  = wsrc[8 * 4 + kq],  wq9  = wsrc[9 * 4 + kq];
    f4 wq10 = wsrc[10 * 4 + kq], wq11 = wsrc[11 * 4 + kq];
    f4 wq12 = wsrc[12 * 4 + kq], wq13 = wsrc[13 * 4 + kq];
    f4 wq14 = wsrc[14 * 4 + kq], wq15 = wsrc[15 * 4 + kq];
    // PIN: opaque def — compiler must keep these register-resident.
    asm volatile("" : "+v"(wq0), "+v"(wq1), "+v"(wq2), "+v"(wq3),
                      "+v"(wq4), "+v"(wq5), "+v"(wq6), "+v"(wq7),
                      "+v"(wq8), "+v"(wq9), "+v"(wq10), "+v"(wq11),
                      "+v"(wq12), "+v"(wq13), "+v"(wq14), "+v"(wq15));
    float c_reg = 0.f;
    const int dcol = dim;

    for (int t = 0; t < T_; ++t) {
      const int buf = t & 1;
      // prefetch gate-packed xg (ONE float4 per finalize lane)
      f4 xgv = {0.f, 0.f, 0.f, 0.f};
      if ((lane & 15) == 0)
        xgv = *(const f4*)(xg2 + ((size_t)(t * 32 + b) * 256 + dcol) * 4);
      if (t == 0) {
        if (tid < 128) ((float2*)h_s[0])[tid] = make_float2(0.f, 0.f);
      } else if (tid < 128) {
        const unsigned long long* pp = hsq + (size_t)((t - 1) * 32 + b) * 128 + tid;
        unsigned long long v = aload_u64(pp);
        int spins = 0;
        while (bad_u64(v)) {
          if (++spins > 16) __builtin_amdgcn_s_sleep(1);
          v = aload_u64(pp);
        }
        union { unsigned long long u; float2 f; } H; H.u = v;
        ((float2*)h_s[buf])[tid] = H.f;
      }
      __syncthreads();   // the ONLY barrier per step

      const f4* h4 = (const f4*)h_s[buf];
      float s = 0.f;
#define LSTEP(i4, W)                                                         \
      {                                                                      \
        const f4 hv = h4[i4 * 4 + kq];                                       \
        s = fmaf(W.x, hv.x, s); s = fmaf(W.y, hv.y, s);                      \
        s = fmaf(W.z, hv.z, s); s = fmaf(W.w, hv.w, s);                      \
      }
      LSTEP(0, wq0)   LSTEP(1, wq1)   LSTEP(2, wq2)   LSTEP(3, wq3)
      LSTEP(4, wq4)   LSTEP(5, wq5)   LSTEP(6, wq6)   LSTEP(7, wq7)
      LSTEP(8, wq8)   LSTEP(9, wq9)   LSTEP(10, wq10) LSTEP(11, wq11)
      LSTEP(12, wq12) LSTEP(13, wq13) LSTEP(14, wq14) LSTEP(15, wq15)
#undef LSTEP
      s += __shfl_xor(s, 1); s += __shfl_xor(s, 2);   // merge 4 k-quarters
      const int base = lane & 48;
      const float gi = __shfl(s, base);
      const float gf = __shfl(s, base + 4);
      const float gg = __shfl(s, base + 8);
      const float go = __shfl(s, base + 12);
      if ((lane & 15) == 0) {
        const float i_ = sigm_f(gi + xgv.x);
        const float f_ = sigm_f(gf + xgv.y);
        const float g_ = tanh_f(gg + xgv.z);
        const float o_ = sigm_f(go + xgv.w);
        c_reg = fmaf(f_, c_reg, i_ * g_);
        const float ht = o_ * tanh_f(c_reg);
        astore_f(hseq + (size_t)(t * 32 + b) * 256 + dcol, ht);
      }
      (void)gt;
    }
  } else {
    // ===================== cfc (batch b, rows 16*cb16..) =====================
    const int bix = blockIdx.x - 512;
    const int b = bix >> 4, cb16 = bix & 15;
    const int r_in = lane >> 4, kq16 = lane & 15;
    const int ci = cb16 * 16 + 4 * w + r_in;
    const float it_i = 1.0f / tau[ci];
#define WCLOAD(i4)                                                           \
    (f4){wc_elem(W_A, M2, tau, ci, it_i, (i4 * 16 + kq16) * 4 + 0),          \
         wc_elem(W_A, M2, tau, ci, it_i, (i4 * 16 + kq16) * 4 + 1),          \
         wc_elem(W_A, M2, tau, ci, it_i, (i4 * 16 + kq16) * 4 + 2),          \
         wc_elem(W_A, M2, tau, ci, it_i, (i4 * 16 + kq16) * 4 + 3)}
    f4 wc0  = WCLOAD(0),  wc1  = WCLOAD(1),  wc2  = WCLOAD(2);
    f4 wc3  = WCLOAD(3),  wc4  = WCLOAD(4),  wc5  = WCLOAD(5);
    f4 wc6  = WCLOAD(6),  wc7  = WCLOAD(7),  wc8  = WCLOAD(8);
    f4 wc9  = WCLOAD(9),  wc10 = WCLOAD(10), wc11 = WCLOAD(11);
#undef WCLOAD
    asm volatile("" : "+v"(wc0), "+v"(wc1), "+v"(wc2), "+v"(wc3),
                      "+v"(wc4), "+v"(wc5), "+v"(wc6), "+v"(wc7),
                      "+v"(wc8), "+v"(wc9), "+v"(wc10), "+v"(wc11));
    float2 isg2 = make_float2(0.f, 0.f);
    if (tid < 128) isg2 = make_float2(1.0f / sigma[2 * tid], 1.0f / sigma[2 * tid + 1]);
    const bool fin = (kq16 == 0);

    for (int t = 0; t < T_; ++t) {
      const int buf = t & 1;
      const float ts = ts_all[b * T_ + t];   // broadcast
      float bx_v = 0.f;
      if (fin) bx_v = bx2[(size_t)(t * 32 + b) * 256 + ci];

      if (t == 0) {
        if (tid < 128) {
          const float2 z = make_float2(0.f, 0.f);
          ((float2*)h_s[0])[tid] = z;
          float2* qrow = (float2*)q_s[0];
          qrow[tid] = z; qrow[128 + tid] = z; qrow[256 + tid] = z;
        }
      } else if (tid < 128) {
        const size_t base = (size_t)((t - 1) * 32 + b) * 128 + tid;
        const unsigned long long* pc = hcsq + base;
        const unsigned long long* ph = hsq + base;
        unsigned long long vc = aload_u64(pc);
        unsigned long long vh = aload_u64(ph);
        int spins = 0;
        while (bad_u64(vc) || bad_u64(vh)) {
          if (++spins > 16) __builtin_amdgcn_s_sleep(1);
          vc = aload_u64(pc);
          vh = aload_u64(ph);
        }
        union { unsigned long long u; float2 f; } C, H;
        C.u = vc; H.u = vh;
        const float2 hcv = make_float2(C.f.x + H.f.x, C.f.y + H.f.y);
        ((float2*)h_s[buf])[tid] = hcv;
        float2* qrow = (float2*)q_s[buf];
        qrow[tid]       = make_float2(ts * hcv.x, ts * hcv.y);
        qrow[128 + tid] = make_float2(ts * tanh_f(hcv.x * isg2.x),
                                      ts * tanh_f(hcv.y * isg2.y));
        qrow[256 + tid] = make_float2(ts * (ts * hcv.x), ts * (ts * hcv.y));
      }
      __syncthreads();   // the ONLY barrier per step

      const f4* q4 = (const f4*)q_s[buf];
      float s = 0.f;
#define CSTEP(i4, W)                                                         \
      {                                                                      \
        const f4 qv = q4[i4 * 16 + kq16];                                    \
        s = fmaf(W.x, qv.x, s); s = fmaf(W.y, qv.y, s);                      \
        s = fmaf(W.z, qv.z, s); s = fmaf(W.w, qv.w, s);                      \
      }
      CSTEP(0, wc0)  CSTEP(1, wc1)  CSTEP(2, wc2)  CSTEP(3, wc3)
      CSTEP(4, wc4)  CSTEP(5, wc5)  CSTEP(6, wc6)  CSTEP(7, wc7)
      CSTEP(8, wc8)  CSTEP(9, wc9)  CSTEP(10, wc10) CSTEP(11, wc11)
#undef CSTEP
      s += __shfl_xor(s, 1); s += __shfl_xor(s, 2);
      s += __shfl_xor(s, 4); s += __shfl_xor(s, 8);
      if (fin) {
        const float hc_own = h_s[buf][ci];
        const float hn_p = hc_own + s + ts * bx_v * it_i;
        astore_f(hcseq + (size_t)(t * 32 + b) * 256 + ci, hn_p);
      }
      (void)r_in;
    }
  }

  // ======== fused output tail: y rows [4*blockIdx.x, +4), WCT via LDS ========
  __syncthreads();
  {
    if (tid < 128) {
      size_t bases[4];
#pragma unroll
      for (int i = 0; i < 4; ++i) {
        const int row = 4 * (int)blockIdx.x + i;    // = b*128 + t
        const int bb = row >> 7, tt = row & 127;
        bases[i] = (size_t)(tt * 32 + bb) * 128 + tid;
      }
      unsigned long long vc[4], vh[4];
      bool again; int spins = 0;
      do {
        again = false;
#pragma unroll
        for (int i = 0; i < 4; ++i) {
          vc[i] = aload_u64(hcsq + bases[i]);
          vh[i] = aload_u64(hsq + bases[i]);
        }
#pragma unroll
        for (int i = 0; i < 4; ++i)
          if (bad_u64(vc[i]) || bad_u64(vh[i])) again = true;
        if (again && ++spins > 16) __builtin_amdgcn_s_sleep(1);
      } while (again);
#pragma unroll
      for (int i = 0; i < 4; ++i) {
        union { unsigned long long u; float2 f; } C, H;
        C.u = vc[i]; H.u = vh[i];
        ((float2*)(ys_s + i * 256))[tid] =
            make_float2(C.f.x + H.f.x, C.f.y + H.f.y);
      }
    }
    __syncthreads();
    // wave w computes row (4*bix + w); lane -> cols {2*lane, 2*lane+1}
    const int row = 4 * (int)blockIdx.x + w;
    float2 acc = ((const float2*)bC)[lane];
    const float4* wct4 = (const float4*)WCT;
    for (int chunk = 0; chunk < 16; ++chunk) {
      // stage WCT k-rows [16*chunk, +16): 2048 floats, 2 float4/thread
      ((float4*)wct_s)[2 * tid]     = wct4[chunk * 512 + 2 * tid];
      ((float4*)wct_s)[2 * tid + 1] = wct4[chunk * 512 + 2 * tid + 1];
      __syncthreads();
#pragma unroll
      for (int kk = 0; kk < 16; ++kk) {
        const float hv = ys_s[w * 256 + chunk * 16 + kk];      // LDS broadcast
        const float2 wv = ((const float2*)wct_s)[kk * 64 + lane];
        acc.x = fmaf(wv.x, hv, acc.x);
        acc.y = fmaf(wv.y, hv, acc.y);
      }
      __syncthreads();
    }
    ((float2*)(y + (size_t)row * 128))[lane] = acc;
  }
}

extern "C" void kernel_launch(void* const* d_in, const int* in_sizes, int n_in,
                              void* d_out, int out_size, void* d_ws, size_t ws_size,
                              hipStream_t stream) {
  const float* x     = (const float*)d_in[0];
  const float* tspan = (const float*)d_in[1];
  const float* tau   = (const float*)d_in[2];
  const float* sigma = (const float*)d_in[3];
  const float* W_A   = (const float*)d_in[4];
  const float* W_B   = (const float*)d_in[5];
  const float* b_B   = (const float*)d_in[6];
  const float* W_C   = (const float*)d_in[7];
  const float* b_C   = (const float*)d_in[8];
  const float* W_ih  = (const float*)d_in[9];
  const float* W_hh  = (const float*)d_in[10];
  const float* b_ih  = (const float*)d_in[11];
  const float* b_hh  = (const float*)d_in[12];
  float* ws = (float*)d_ws;
  float* y = (float*)d_out;

  prep_kernel<<<1153, 256, 0, stream>>>(W_ih, W_B, b_ih, b_hh, b_B, W_C,
                                        W_A, tau, ws);
  xgt_kernel<<<dim3(128, 5), 256, 0, stream>>>(x, ws + OFF_WCOMBT, ws + OFF_BIAS,
                                               ws + OFF_XG2, ws + OFF_BX2);
  recur_bp_kernel<<<1024, 256, 0, stream>>>(
      tspan, tau, sigma, W_hh, W_A, ws + OFF_M2, ws + OFF_XG2, ws + OFF_BX2,
      ws + OFF_HSEQ, ws + OFF_HCSEQ, ws + OFF_WCT, b_C, y);
}

// Round 17
// 350.499 us; speedup vs baseline: 1.2786x; 1.2786x over previous
//
#include <hip/hip_runtime.h>
#include <math.h>

#define T_ 128

// ws offsets (floats)
#define OFF_M2      0         // [256][256]
#define OFF_WCOMBT  65536     // [128][1280]
#define OFF_BIAS    229376    // [1280]
#define OFF_WCT     230656    // [256][128]
#define OFF_XG2     263424    // [128 t][32 b][1024 c]   (c = gate*256 + dim)
#define OFF_BX2     4457728   // [128 t][32 b][256 d]
#define OFF_HSEQ    5506304   // [128 t][32 b][256 d]  (ht from LSTM chain)
#define OFF_HCSEQ   6554880   // [128 t][32 b][256 d]  (hn_partial from cfc chain)

#define SENTB 0xFFFFFFFFu

typedef float f4 __attribute__((ext_vector_type(4)));

__device__ __forceinline__ float sigm_f(float x) { return 1.0f / (1.0f + __expf(-x)); }
__device__ __forceinline__ float tanh_f(float x) { return 1.0f - 2.0f / (__expf(2.0f * x) + 1.0f); }

__device__ __forceinline__ unsigned long long aload_u64(const unsigned long long* p) {
  return __hip_atomic_load(p, __ATOMIC_RELAXED, __HIP_MEMORY_SCOPE_AGENT);
}
__device__ __forceinline__ void astore_f(float* p, float v) {
  __hip_atomic_store(p, v, __ATOMIC_RELAXED, __HIP_MEMORY_SCOPE_AGENT);
}
__device__ __forceinline__ bool bad_u64(unsigned long long v) {
  return (unsigned)v == SENTB || (unsigned)(v >> 32) == SENTB;
}

// ---------------- prep: WcombT, bias, WCT, M2, sentinel fill ----------------
__global__ __launch_bounds__(256) void prep_kernel(
    const float* __restrict__ W_ih, const float* __restrict__ W_B,
    const float* __restrict__ b_ih, const float* __restrict__ b_hh,
    const float* __restrict__ b_B,  const float* __restrict__ W_C,
    const float* __restrict__ W_A,  const float* __restrict__ tau,
    float* __restrict__ ws) {
  __shared__ float adrow[256];
  const int blk = blockIdx.x, tid = threadIdx.x;
  if (blk < 640) {            // WcombT[k][c], 163840 elems
    const int idx = blk * 256 + tid;
    const int k = idx / 1280, c = idx - k * 1280;
    ws[OFF_WCOMBT + idx] = (c < 1024) ? W_ih[c * 128 + k] : W_B[(c - 1024) * 128 + k];
  } else if (blk == 640) {    // bias[1280]
#pragma unroll
    for (int i = 0; i < 5; ++i) {
      const int id = i * 256 + tid;
      ws[OFF_BIAS + id] = (id < 1024) ? (b_ih[id] + b_hh[id]) : b_B[id - 1024];
    }
  } else if (blk < 769) {     // WCT[k][o], 32768
    const int idx = (blk - 641) * 256 + tid;
    const int k = idx >> 7, o = idx & 127;
    ws[OFF_WCT + idx] = W_C[o * 256 + k];
  } else if (blk < 1025) {    // M2 row i = (W_A D)(W_A D), D = diag(1/tau)
    const int i = blk - 769, k = tid;
    const float itk = 1.0f / tau[k];
    adrow[k] = W_A[i * 256 + k] * itk;
    __syncthreads();
    float s = 0.f;
#pragma unroll 8
    for (int m = 0; m < 256; ++m)
      s = fmaf(adrow[m], W_A[m * 256 + k], s);
    ws[OFF_M2 + i * 256 + k] = s * itk;
  } else {                    // sentinel fill (0xFFFFFFFF dwords), 8 MB
    uint4* dst = (uint4*)(ws + OFF_HSEQ);
    const uint4 sv = make_uint4(SENTB, SENTB, SENTB, SENTB);
    const int tg = (blk - 1025) * 256 + tid;  // 32768 threads x 16 uint4
#pragma unroll
    for (int i = 0; i < 16; ++i) dst[tg + i * 32768] = sv;
  }
}

// ---------------- xg/Bx precompute v2: 32 rows/block, 4-row reuse of WT ------
__global__ __launch_bounds__(256) void xgt_kernel(
    const float* __restrict__ x, const float* __restrict__ WT,
    const float* __restrict__ bias, float* __restrict__ xg2,
    float* __restrict__ bx2) {
  __shared__ float xs[32 * 128];   // 16 KB
  const int tid = threadIdx.x;
  const int rt = blockIdx.x, ct = blockIdx.y;
  {
    const float4* src4 = (const float4*)(x + (size_t)rt * 4096);
    float4* d4 = (float4*)xs;
#pragma unroll
    for (int v = 0; v < 4; ++v) d4[v * 256 + tid] = src4[v * 256 + tid];
  }
  __syncthreads();
  const int rg = tid >> 5, cg = tid & 31;
  const int c0 = ct * 256 + cg * 8;
  const float4* b4 = (const float4*)(bias + c0);
  const float4 bA = b4[0], bB = b4[1];
  float a[4][8];
#pragma unroll
  for (int i = 0; i < 4; ++i) {
    a[i][0] = bA.x; a[i][1] = bA.y; a[i][2] = bA.z; a[i][3] = bA.w;
    a[i][4] = bB.x; a[i][5] = bB.y; a[i][6] = bB.z; a[i][7] = bB.w;
  }
  const float4* xr0 = (const float4*)(xs + (rg * 4 + 0) * 128);
  const float4* xr1 = (const float4*)(xs + (rg * 4 + 1) * 128);
  const float4* xr2 = (const float4*)(xs + (rg * 4 + 2) * 128);
  const float4* xr3 = (const float4*)(xs + (rg * 4 + 3) * 128);
#pragma unroll 2
  for (int k4 = 0; k4 < 32; ++k4) {
    const float4 xv0 = xr0[k4], xv1 = xr1[k4], xv2 = xr2[k4], xv3 = xr3[k4];
    const float xk[4][4] = {
        {xv0.x, xv0.y, xv0.z, xv0.w}, {xv1.x, xv1.y, xv1.z, xv1.w},
        {xv2.x, xv2.y, xv2.z, xv2.w}, {xv3.x, xv3.y, xv3.z, xv3.w}};
#pragma unroll
    for (int kk = 0; kk < 4; ++kk) {
      const float4* wp = (const float4*)(WT + (k4 * 4 + kk) * 1280 + c0);
      const float4 wA = wp[0], wB = wp[1];
      const float wv[8] = {wA.x, wA.y, wA.z, wA.w, wB.x, wB.y, wB.z, wB.w};
#pragma unroll
      for (int i = 0; i < 4; ++i)
#pragma unroll
        for (int j = 0; j < 8; ++j)
          a[i][j] = fmaf(wv[j], xk[i][kk], a[i][j]);
    }
  }
#pragma unroll
  for (int i = 0; i < 4; ++i) {
    const int row = rt * 32 + rg * 4 + i;   // = b*128 + t
    const int b = row >> 7, t = row & 127;
    float* dst = (ct < 4)
        ? xg2 + (size_t)(t * 32 + b) * 1024 + ct * 256 + cg * 8
        : bx2 + (size_t)(t * 32 + b) * 256 + cg * 8;
    float4* d4 = (float4*)dst;
    d4[0] = make_float4(a[i][0], a[i][1], a[i][2], a[i][3]);
    d4[1] = make_float4(a[i][4], a[i][5], a[i][6], a[i][7]);
  }
}

__device__ __forceinline__ float wc_elem(
    const float* __restrict__ W_A, const float* __restrict__ M2,
    const float* __restrict__ tau, int ci, float it_i, int kp) {
  if (kp < 256)      return W_A[ci * 256 + kp] / tau[kp];
  else if (kp < 512) return W_A[ci * 256 + (kp - 256)] * it_i;
  else               return 0.5f * M2[ci * 256 + (kp - 512)];
}

// ---------------- recurrence + fused output: 1024 blocks ----------------
// blocks [0,512): LSTM,  b = bix>>4, cb16 = bix&15, owns dims [16cb16, +16)
// blocks [512,1024): cfc, same mapping for rows.
// Tail: 4 y-rows per block, COLUMN-SPLIT across waves (each wave streams only
// its 32-col slice of WCT once -> 128 KB/block, no LDS staging, no barriers).
__global__ __launch_bounds__(256, 4) void recur_bp_kernel(
    const float* __restrict__ ts_all, const float* __restrict__ tau,
    const float* __restrict__ sigma, const float* __restrict__ W_hh,
    const float* __restrict__ W_A, const float* __restrict__ M2,
    const float* __restrict__ xg2, const float* __restrict__ bx2,
    float* __restrict__ hseq, float* __restrict__ hcseq,
    const float* __restrict__ WCT, const float* __restrict__ bC,
    float* __restrict__ y) {
  const int tid = threadIdx.x;
  const int lane = tid & 63, w = tid >> 6;
  const unsigned long long* hsq  = (const unsigned long long*)hseq;
  const unsigned long long* hcsq = (const unsigned long long*)hcseq;

  __shared__ float h_s[2][256];   // staged state (h or true hc), double-buffered
  __shared__ float q_s[2][768];   // cfc q vector (also out-tail scratch)

  if (blockIdx.x < 512) {
    // ===================== LSTM (batch b, dims 16*cb16..) =====================
    const int b = blockIdx.x >> 4, cb16 = blockIdx.x & 15;
    const int kq = lane & 3;
    const int gt = (lane >> 2) & 3;
    const int dim = cb16 * 16 + 4 * w + (lane >> 4);
    const int grow = gt * 256 + dim;
    // INTERLEAVED k: this lane handles float4 indices i4*4 + kq.
    const f4* wsrc = (const f4*)(W_hh + grow * 256);
    f4 wq0  = wsrc[0 * 4 + kq],  wq1  = wsrc[1 * 4 + kq];
    f4 wq2  = wsrc[2 * 4 + kq],  wq3  = wsrc[3 * 4 + kq];
    f4 wq4  = wsrc[4 * 4 + kq],  wq5  = wsrc[5 * 4 + kq];
    f4 wq6  = wsrc[6 * 4 + kq],  wq7  = wsrc[7 * 4 + kq];
    f4 wq8  = wsrc[8 * 4 + kq],  wq9  = wsrc[9 * 4 + kq];
    f4 wq10 = wsrc[10 * 4 + kq], wq11 = wsrc[11 * 4 + kq];
    f4 wq12 = wsrc[12 * 4 + kq], wq13 = wsrc[13 * 4 + kq];
    f4 wq14 = wsrc[14 * 4 + kq], wq15 = wsrc[15 * 4 + kq];
    // PIN: opaque def — compiler must keep these register-resident.
    asm volatile("" : "+v"(wq0), "+v"(wq1), "+v"(wq2), "+v"(wq3),
                      "+v"(wq4), "+v"(wq5), "+v"(wq6), "+v"(wq7),
                      "+v"(wq8), "+v"(wq9), "+v"(wq10), "+v"(wq11),
                      "+v"(wq12), "+v"(wq13), "+v"(wq14), "+v"(wq15));
    float c_reg = 0.f;
    const int dcol = dim;

    for (int t = 0; t < T_; ++t) {
      const int buf = t & 1;
      float xgi = 0.f, xgf = 0.f, xgg = 0.f, xgo = 0.f;
      if ((lane & 15) == 0) {
        const float* xp = xg2 + (size_t)(t * 32 + b) * 1024 + dcol;
        xgi = xp[0]; xgf = xp[256]; xgg = xp[512]; xgo = xp[768];
      }
      if (t == 0) {
        if (tid < 128) ((float2*)h_s[0])[tid] = make_float2(0.f, 0.f);
      } else if (tid < 128) {
        const unsigned long long* pp = hsq + (size_t)((t - 1) * 32 + b) * 128 + tid;
        unsigned long long v = aload_u64(pp);
        int spins = 0;
        while (bad_u64(v)) {
          if (++spins > 16) __builtin_amdgcn_s_sleep(1);
          v = aload_u64(pp);
        }
        union { unsigned long long u; float2 f; } H; H.u = v;
        ((float2*)h_s[buf])[tid] = H.f;
      }
      __syncthreads();   // the ONLY barrier per step

      const f4* h4 = (const f4*)h_s[buf];
      float s = 0.f;
#define LSTEP(i4, W)                                                         \
      {                                                                      \
        const f4 hv = h4[i4 * 4 + kq];                                       \
        s = fmaf(W.x, hv.x, s); s = fmaf(W.y, hv.y, s);                      \
        s = fmaf(W.z, hv.z, s); s = fmaf(W.w, hv.w, s);                      \
      }
      LSTEP(0, wq0)   LSTEP(1, wq1)   LSTEP(2, wq2)   LSTEP(3, wq3)
      LSTEP(4, wq4)   LSTEP(5, wq5)   LSTEP(6, wq6)   LSTEP(7, wq7)
      LSTEP(8, wq8)   LSTEP(9, wq9)   LSTEP(10, wq10) LSTEP(11, wq11)
      LSTEP(12, wq12) LSTEP(13, wq13) LSTEP(14, wq14) LSTEP(15, wq15)
#undef LSTEP
      s += __shfl_xor(s, 1); s += __shfl_xor(s, 2);   // merge 4 k-quarters
      const int base = lane & 48;
      const float gi = __shfl(s, base);
      const float gf = __shfl(s, base + 4);
      const float gg = __shfl(s, base + 8);
      const float go = __shfl(s, base + 12);
      if ((lane & 15) == 0) {
        const float i_ = sigm_f(gi + xgi);
        const float f_ = sigm_f(gf + xgf);
        const float g_ = tanh_f(gg + xgg);
        const float o_ = sigm_f(go + xgo);
        c_reg = fmaf(f_, c_reg, i_ * g_);
        const float ht = o_ * tanh_f(c_reg);
        astore_f(hseq + (size_t)(t * 32 + b) * 256 + dcol, ht);
      }
      (void)gt;
    }
  } else {
    // ===================== cfc (batch b, rows 16*cb16..) =====================
    const int bix = blockIdx.x - 512;
    const int b = bix >> 4, cb16 = bix & 15;
    const int r_in = lane >> 4, kq16 = lane & 15;
    const int ci = cb16 * 16 + 4 * w + r_in;
    const float it_i = 1.0f / tau[ci];
#define WCLOAD(i4)                                                           \
    (f4){wc_elem(W_A, M2, tau, ci, it_i, (i4 * 16 + kq16) * 4 + 0),          \
         wc_elem(W_A, M2, tau, ci, it_i, (i4 * 16 + kq16) * 4 + 1),          \
         wc_elem(W_A, M2, tau, ci, it_i, (i4 * 16 + kq16) * 4 + 2),          \
         wc_elem(W_A, M2, tau, ci, it_i, (i4 * 16 + kq16) * 4 + 3)}
    f4 wc0  = WCLOAD(0),  wc1  = WCLOAD(1),  wc2  = WCLOAD(2);
    f4 wc3  = WCLOAD(3),  wc4  = WCLOAD(4),  wc5  = WCLOAD(5);
    f4 wc6  = WCLOAD(6),  wc7  = WCLOAD(7),  wc8  = WCLOAD(8);
    f4 wc9  = WCLOAD(9),  wc10 = WCLOAD(10), wc11 = WCLOAD(11);
#undef WCLOAD
    asm volatile("" : "+v"(wc0), "+v"(wc1), "+v"(wc2), "+v"(wc3),
                      "+v"(wc4), "+v"(wc5), "+v"(wc6), "+v"(wc7),
                      "+v"(wc8), "+v"(wc9), "+v"(wc10), "+v"(wc11));
    float2 isg2 = make_float2(0.f, 0.f);
    if (tid < 128) isg2 = make_float2(1.0f / sigma[2 * tid], 1.0f / sigma[2 * tid + 1]);
    const bool fin = (kq16 == 0);

    for (int t = 0; t < T_; ++t) {
      const int buf = t & 1;
      const float ts = ts_all[b * T_ + t];   // broadcast
      float bx_v = 0.f;
      if (fin) bx_v = bx2[(size_t)(t * 32 + b) * 256 + ci];

      if (t == 0) {
        if (tid < 128) {
          const float2 z = make_float2(0.f, 0.f);
          ((float2*)h_s[0])[tid] = z;
          float2* qrow = (float2*)q_s[0];
          qrow[tid] = z; qrow[128 + tid] = z; qrow[256 + tid] = z;
        }
      } else if (tid < 128) {
        const size_t base = (size_t)((t - 1) * 32 + b) * 128 + tid;
        const unsigned long long* pc = hcsq + base;
        const unsigned long long* ph = hsq + base;
        unsigned long long vc = aload_u64(pc);
        unsigned long long vh = aload_u64(ph);
        int spins = 0;
        while (bad_u64(vc) || bad_u64(vh)) {
          if (++spins > 16) __builtin_amdgcn_s_sleep(1);
          vc = aload_u64(pc);
          vh = aload_u64(ph);
        }
        union { unsigned long long u; float2 f; } C, H;
        C.u = vc; H.u = vh;
        const float2 hcv = make_float2(C.f.x + H.f.x, C.f.y + H.f.y);
        ((float2*)h_s[buf])[tid] = hcv;
        float2* qrow = (float2*)q_s[buf];
        qrow[tid]       = make_float2(ts * hcv.x, ts * hcv.y);
        qrow[128 + tid] = make_float2(ts * tanh_f(hcv.x * isg2.x),
                                      ts * tanh_f(hcv.y * isg2.y));
        qrow[256 + tid] = make_float2(ts * (ts * hcv.x), ts * (ts * hcv.y));
      }
      __syncthreads();   // the ONLY barrier per step

      const f4* q4 = (const f4*)q_s[buf];
      float s = 0.f;
#define CSTEP(i4, W)                                                         \
      {                                                                      \
        const f4 qv = q4[i4 * 16 + kq16];                                    \
        s = fmaf(W.x, qv.x, s); s = fmaf(W.y, qv.y, s);                      \
        s = fmaf(W.z, qv.z, s); s = fmaf(W.w, qv.w, s);                      \
      }
      CSTEP(0, wc0)  CSTEP(1, wc1)  CSTEP(2, wc2)  CSTEP(3, wc3)
      CSTEP(4, wc4)  CSTEP(5, wc5)  CSTEP(6, wc6)  CSTEP(7, wc7)
      CSTEP(8, wc8)  CSTEP(9, wc9)  CSTEP(10, wc10) CSTEP(11, wc11)
#undef CSTEP
      s += __shfl_xor(s, 1); s += __shfl_xor(s, 2);
      s += __shfl_xor(s, 4); s += __shfl_xor(s, 8);
      if (fin) {
        const float hc_own = h_s[buf][ci];
        const float hn_p = hc_own + s + ts * bx_v * it_i;
        astore_f(hcseq + (size_t)(t * 32 + b) * 256 + ci, hn_p);
      }
      (void)r_in;
    }
  }

  // ======== fused output tail: y rows [4*blockIdx.x, +4), column-split ========
  __syncthreads();
  {
    float* ys = &q_s[0][0];   // 1024-float scratch (hc = hn_partial + ht)
    if (tid < 128) {
      size_t bases[4];
#pragma unroll
      for (int i = 0; i < 4; ++i) {
        const int row = 4 * (int)blockIdx.x + i;    // = b*128 + t
        const int bb = row >> 7, tt = row & 127;
        bases[i] = (size_t)(tt * 32 + bb) * 128 + tid;
      }
      unsigned long long vc[4], vh[4];
      bool again; int spins = 0;
      do {
        again = false;
#pragma unroll
        for (int i = 0; i < 4; ++i) {
          vc[i] = aload_u64(hcsq + bases[i]);
          vh[i] = aload_u64(hsq + bases[i]);
        }
#pragma unroll
        for (int i = 0; i < 4; ++i)
          if (bad_u64(vc[i]) || bad_u64(vh[i])) again = true;
        if (again && ++spins > 16) __builtin_amdgcn_s_sleep(1);
      } while (again);
#pragma unroll
      for (int i = 0; i < 4; ++i) {
        union { unsigned long long u; float2 f; } C, H;
        C.u = vc[i]; H.u = vh[i];
        ((float2*)(ys + i * 256))[tid] =
            make_float2(C.f.x + H.f.x, C.f.y + H.f.y);
      }
    }
    __syncthreads();
    // column-split: wave w owns cols [32w, 32w+32); lane -> col c, rows {2rp, 2rp+1}
    const int c = 32 * w + (lane & 31);
    const int rp = lane >> 5;
    const float* y0 = ys + (2 * rp) * 256;
    const float* y1 = ys + (2 * rp + 1) * 256;
    float a0 = bC[c], a1 = bC[c];
#pragma unroll 8
    for (int k = 0; k < 256; ++k) {
      const float wv = WCT[k * 128 + c];   // 128B coalesced per wave, streamed once
      a0 = fmaf(wv, y0[k], a0);            // LDS broadcast (2 addrs/wave = free)
      a1 = fmaf(wv, y1[k], a1);
    }
    const int rowbase = 4 * (int)blockIdx.x;
    y[(size_t)(rowbase + 2 * rp) * 128 + c]     = a0;
    y[(size_t)(rowbase + 2 * rp + 1) * 128 + c] = a1;
  }
}

extern "C" void kernel_launch(void* const* d_in, const int* in_sizes, int n_in,
                              void* d_out, int out_size, void* d_ws, size_t ws_size,
                              hipStream_t stream) {
  const float* x     = (const float*)d_in[0];
  const float* tspan = (const float*)d_in[1];
  const float* tau   = (const float*)d_in[2];
  const float* sigma = (const float*)d_in[3];
  const float* W_A   = (const float*)d_in[4];
  const float* W_B   = (const float*)d_in[5];
  const float* b_B   = (const float*)d_in[6];
  const float* W_C   = (const float*)d_in[7];
  const float* b_C   = (const float*)d_in[8];
  const float* W_ih  = (const float*)d_in[9];
  const float* W_hh  = (const float*)d_in[10];
  const float* b_ih  = (const float*)d_in[11];
  const float* b_hh  = (const float*)d_in[12];
  float* ws = (float*)d_ws;
  float* y = (float*)d_out;

  prep_kernel<<<1153, 256, 0, stream>>>(W_ih, W_B, b_ih, b_hh, b_B, W_C,
                                        W_A, tau, ws);
  xgt_kernel<<<dim3(128, 5), 256, 0, stream>>>(x, ws + OFF_WCOMBT, ws + OFF_BIAS,
                                               ws + OFF_XG2, ws + OFF_BX2);
  recur_bp_kernel<<<1024, 256, 0, stream>>>(
      tspan, tau, sigma, W_hh, W_A, ws + OFF_M2, ws + OFF_XG2, ws + OFF_BX2,
      ws + OFF_HSEQ, ws + OFF_HCSEQ, ws + OFF_WCT, b_C, y);
}